// Round 11
// baseline (3942.671 us; speedup 1.0000x reference)
//
#include <hip/hip_runtime.h>
#include <cstdint>

typedef unsigned short u16;
typedef unsigned int u32;
typedef unsigned long long u64;
typedef float f32x4 __attribute__((ext_vector_type(4)));
typedef short s16x8 __attribute__((ext_vector_type(8)));

#define DEV static __device__ __forceinline__

#define TT 128
#define BB 256
#define OBSD 128
#define HHD 512
#define AD 18
#define GGD 2048
#define MMD 32768

DEV u16 f2bf(float f) {
  u32 u = __builtin_bit_cast(u32, f);
  u += 0x7fffu + ((u >> 16) & 1u);
  return (u16)(u >> 16);
}
DEV float bf2f(u16 h) { return __builtin_bit_cast(float, ((u32)h) << 16); }

DEV f32x4 mfma16x16x32(s16x8 a, s16x8 b, f32x4 c) {
  // D = A*B + C, C/D layout: col=lane&15, row=(lane>>4)*4+reg  [m89/m91]
  asm("v_mfma_f32_16x16x32_bf16 %0, %1, %2, %0" : "+v"(c) : "v"(a), "v"(b));
  return c;
}
// Inline-asm MFMA: hazard recognizer can't see it -> manual wait states (proven R3).
DEV void fence_mfma_read(f32x4& x) { asm volatile("s_nop 7" : "+v"(x)); }
DEV void fence_mfma_srcc(f32x4& x) { asm volatile("s_nop 1" : "+v"(x)); }

// async global->LDS, 16B/lane; LDS dest is wave-uniform base + lane*16 (m97/m104)
typedef __attribute__((address_space(3))) char lds_char;
typedef __attribute__((address_space(1))) const char gl_char;
DEV void gload16(const char* g, char* l) {
  __builtin_amdgcn_global_load_lds((const gl_char*)g, (lds_char*)l, 16, 0, 0);
}

DEV float sigm(float x) { return 1.f / (1.f + __expf(-x)); }
DEV float tanh_fast(float x) {
  float t = __expf(-2.f * fabsf(x));
  float r = (1.f - t) / (1.f + t);
  return copysignf(r, x);
}

// ---------------- workspace layout (bytes), total ~218MB ----------------
constexpr size_t OFF_FLAGS = 0;          // 262144: slots[rg 16][t 128][ug 32] u32
constexpr size_t OFF_HRING = 524288;     // 524288  (2 x [256][512] bf16)
constexpr size_t OFF_TW0T  = 1048576;    // 131072
constexpr size_t OFF_TW1T  = 1179648;    // 524288
constexpr size_t OFF_AW0T  = 1703936;    // 524288
constexpr size_t OFF_VW0T  = 2228224;    // 524288 (contiguous with AW0T)
constexpr size_t OFF_AW1T  = 2752512;    // 18432
constexpr size_t OFF_VW1T  = 2770944;    // 1024
constexpr size_t OFF_WIH   = 2772992;    // 2097152
constexpr size_t OFF_WHH   = 4870144;    // 2097152
constexpr size_t OFF_BSUM  = 6967296;    // 8192
constexpr size_t OFF_WRC   = 6975488;    // 8192
constexpr size_t OFF_WEMB  = 6983680;    // 147456
constexpr size_t OFF_BCAT  = 7131136;    // 4096
constexpr size_t OFF_OBF   = 8388608;    // 8388608
constexpr size_t OFF_BUF1  = 16777216;   // 33554432  (h1, later hs)
constexpr size_t OFF_BUF2  = 50331648;   // 33554432  (hid)
constexpr size_t OFF_BUF3  = 83886080;   // 134217728 (xg, later hv [32768][1024])

// ---------------- prep: convert/transpose weights, convert o, init h-ring ----------------
__global__ __launch_bounds__(256) void prep(
    const float* __restrict__ o, const float* __restrict__ tW0,
    const float* __restrict__ tW1, const float* __restrict__ aW0,
    const float* __restrict__ vW0, const float* __restrict__ aW1,
    const float* __restrict__ vW1, const float* __restrict__ Wih,
    const float* __restrict__ WhhF, const float* __restrict__ bih,
    const float* __restrict__ bhh, const float* __restrict__ h0,
    const float* __restrict__ done, const float* __restrict__ ab0,
    const float* __restrict__ vb0,
    u16* __restrict__ o_bf, u16* __restrict__ tW0T, u16* __restrict__ tW1T,
    u16* __restrict__ aW0T, u16* __restrict__ vW0T, u16* __restrict__ aW1T,
    u16* __restrict__ vW1T, u16* __restrict__ WihB, u16* __restrict__ WhhB,
    float* __restrict__ bsum, float* __restrict__ wrc, float* __restrict__ wemb,
    float* __restrict__ bcat, u16* __restrict__ hring)
{
  const int total = 4178432;
  for (int id = blockIdx.x * 256 + threadIdx.x; id < total; id += gridDim.x * 256) {
    int i = id;
    if (i < 1048576) {  // o -> bf16, x4
      float4 v = ((const float4*)o)[i];
      u16* dst = o_bf + (size_t)i * 4;
      dst[0] = f2bf(v.x); dst[1] = f2bf(v.y); dst[2] = f2bf(v.z); dst[3] = f2bf(v.w);
      continue;
    }
    i -= 1048576;
    if (i < 65536)  { int n = i >> 7, k = i & 127; tW0T[i] = f2bf(tW0[k * 512 + n]); continue; }
    i -= 65536;
    if (i < 262144) { int n = i >> 9, k = i & 511; tW1T[i] = f2bf(tW1[k * 512 + n]); continue; }
    i -= 262144;
    if (i < 262144) { int n = i >> 9, k = i & 511; aW0T[i] = f2bf(aW0[k * 512 + n]); continue; }
    i -= 262144;
    if (i < 262144) { int n = i >> 9, k = i & 511; vW0T[i] = f2bf(vW0[k * 512 + n]); continue; }
    i -= 262144;
    if (i < 9216)   { int n = i >> 9, k = i & 511; aW1T[i] = f2bf(aW1[k * 18 + n]); continue; }
    i -= 9216;
    if (i < 512)    { vW1T[i] = f2bf(vW1[i]); continue; }
    i -= 512;
    if (i < 1048576){ int g = i >> 9, k = i & 511; WihB[i] = f2bf(Wih[g * 531 + k]); continue; }
    i -= 1048576;
    if (i < 1048576){ WhhB[i] = f2bf(WhhF[i]); continue; }
    i -= 1048576;
    if (i < 2048)   { bsum[i] = bih[i] + bhh[i]; wrc[i] = Wih[i * 531 + 512]; continue; }
    i -= 2048;
    if (i < 36864)  { int j = i >> 11, g = i & 2047; wemb[i] = Wih[g * 531 + 513 + j]; continue; }
    i -= 36864;
    if (i < 1024)   { bcat[i] = (i < 512) ? ab0[i] : vb0[i - 512]; continue; }
    i -= 1024;
    { int b = i >> 9; hring[i] = f2bf(h0[i] * (1.f - done[b])); }  // h_all[0] = h0*keep0
  }
}

// ---------------- bf16 MFMA GEMM: C[M][N] = A[M][K] * Bt[N][K]^T + epilogue ----------------
// Staging via global_load_lds w=16: linear LDS dest, inverse-swizzled global src (rule #21).
// MODE 0: relu(acc + bias[n]) -> bf16
// MODE 1: acc + bias[n] + r[m]*wrc[n] + wemb[a[m]][n] -> bf16 (xg epilogue)
template<int MODE>
__global__ __launch_bounds__(256) void gemm_bt(
    const u16* __restrict__ A, const u16* __restrict__ Bt, u16* __restrict__ C,
    int Mdim, int Ndim, int Kdim,
    const float* __restrict__ bias,
    const float* __restrict__ wrc, const float* __restrict__ wemb,
    const float* __restrict__ rin, const int* __restrict__ ain)
{
  __shared__ __align__(16) char smem[32768];  // A tile 16KB | B tile 16KB
  const int tid = threadIdx.x;
  const int nTn = Ndim >> 7;
  int wg = blockIdx.x;
  {  // XCD-aware swizzle (grid % 8 == 0 for all our launches)
    const int per = gridDim.x >> 3;
    wg = (wg & 7) * per + (wg >> 3);
  }
  const int tm = wg / nTn, tn = wg % nTn;
  const int wid = tid >> 6, lane = tid & 63;
  const int wr = wid >> 1, wc = wid & 1;
  const int l15 = lane & 15, l4 = lane >> 4;

  f32x4 acc[4][4];
#pragma unroll
  for (int i = 0; i < 4; ++i)
#pragma unroll
    for (int j = 0; j < 4; ++j) acc[i][j] = f32x4{0.f, 0.f, 0.f, 0.f};

  const int srow = lane >> 3;               // row within 8-row stripe == row&7
  const int scolb = ((lane & 7) * 16) ^ (srow << 4);  // inverse-swizzled byte col
  const size_t kd2 = (size_t)Kdim * 2;
  const char* Abase = (const char*)(A + (size_t)tm * 128 * Kdim);
  const char* Bbase = (const char*)(Bt + (size_t)tn * 128 * Kdim);
  const char* ga[4]; const char* gb[4]; char* la[4]; char* lb[4];
#pragma unroll
  for (int j = 0; j < 4; ++j) {
    const int row = wid * 32 + j * 8 + srow;
    ga[j] = Abase + (size_t)row * kd2 + scolb;
    gb[j] = Bbase + (size_t)row * kd2 + scolb;
    la[j] = smem + wid * 4096 + j * 1024;
    lb[j] = smem + 16384 + wid * 4096 + j * 1024;
  }

  for (int k0 = 0; k0 < Kdim; k0 += 64) {
    const size_t kb = (size_t)k0 * 2;
#pragma unroll
    for (int j = 0; j < 4; ++j) {
      gload16(ga[j] + kb, la[j]);
      gload16(gb[j] + kb, lb[j]);
    }
    __syncthreads();  // drains vmcnt -> LDS tiles complete
#pragma unroll
    for (int kk = 0; kk < 2; ++kk) {
      s16x8 af[4], bfr[4];
#pragma unroll
      for (int i = 0; i < 4; ++i) {
        int ar = wr * 64 + i * 16 + l15;
        af[i] = *(const s16x8*)(smem + ((ar * 128 + kk * 64 + l4 * 16) ^ ((ar & 7) << 4)));
        int br = wc * 64 + i * 16 + l15;
        bfr[i] = *(const s16x8*)(smem + 16384 + ((br * 128 + kk * 64 + l4 * 16) ^ ((br & 7) << 4)));
      }
#pragma unroll
      for (int i = 0; i < 4; ++i)
#pragma unroll
        for (int j = 0; j < 4; ++j)
          acc[i][j] = mfma16x16x32(af[i], bfr[j], acc[i][j]);
    }
    __syncthreads();
  }

#pragma unroll
  for (int i = 0; i < 4; ++i)
#pragma unroll
    for (int j = 0; j < 4; ++j) fence_mfma_read(acc[i][j]);

#pragma unroll
  for (int i = 0; i < 4; ++i) {
    const int rowb = tm * 128 + wr * 64 + i * 16 + l4 * 4;
    float rv[4]; int av[4];
    if (MODE == 1) {
#pragma unroll
      for (int r = 0; r < 4; ++r) { rv[r] = rin[rowb + r]; av[r] = ain[rowb + r]; }
    }
#pragma unroll
    for (int j = 0; j < 4; ++j) {
      const int col = tn * 128 + wc * 64 + j * 16 + l15;
      const float bs = bias[col];
      if (MODE == 0) {
#pragma unroll
        for (int r = 0; r < 4; ++r) {
          float x = acc[i][j][r] + bs;
          x = fmaxf(x, 0.f);
          C[(size_t)(rowb + r) * Ndim + col] = f2bf(x);
        }
      } else {
        const float wcv = wrc[col];
#pragma unroll
        for (int r = 0; r < 4; ++r) {
          float x = acc[i][j][r] + bs + rv[r] * wcv + wemb[av[r] * GGD + col];
          C[(size_t)(rowb + r) * Ndim + col] = f2bf(x);
        }
      }
    }
  }
}

// ---------------- persistent LSTM scan: 4 chains per wave (latency interleave) ----------------
// 32 blocks (one per ug, 16 units); 4 waves/block; each wave serially services 4
// INDEPENDENT row-group chains (rg = ch*4+wid, rows [rg*16, rg*16+16)). While chain
// A's publish propagates through the LLC, the wave computes chains B,C,D -> sync
// latency hidden in-wave. Per-chain protocol identical to proven R8/R10: sc1 publish
// -> s_waitcnt vmcnt(0) -> flag -> relaxed poll. Barrier = per-producer flag ARRAY
// (32 one-shot slot stores, no RMW serialization); consumer __all-polls 32 slots.
__global__ __launch_bounds__(256, 1) void lstm_seq(
    const u16* __restrict__ xg, const u16* __restrict__ WhhB,
    const float* __restrict__ done, const float* __restrict__ c0,
    u16* __restrict__ hring, u16* __restrict__ hs,
    float* __restrict__ hT, float* __restrict__ cT, u32* __restrict__ slots)
{
  __shared__ __align__(16) char wsm[65536];
  const int tid = threadIdx.x;
  const int ug = blockIdx.x;          // 32 blocks
  const int u0 = ug * 16;

#pragma unroll
  for (int i = 0; i < 16; ++i) {  // stage W_hh slice once: local row lr = gate*16+uu
    int idx = i * 256 + tid;
    int lr = idx >> 6, c8 = idx & 63;
    int g = lr >> 4, uu = lr & 15;
    uint4 v = *(const uint4*)(WhhB + (size_t)(g * 512 + u0 + uu) * 512 + c8 * 8);
    *(uint4*)(wsm + ((lr * 1024 + c8 * 16) ^ ((lr & 7) << 4))) = v;
  }
  __syncthreads();  // once, before the loop

  const int wid = tid >> 6, lane = tid & 63;
  const int l15 = lane & 15, l4 = lane >> 4;
  const int u = u0 + l15;

  // chain state (all statically indexed after unroll — rule #20)
  float creg[4][4], kc[4][4], kn[4][4];
  u16 xpf[4][16];
#pragma unroll
  for (int ch = 0; ch < 4; ++ch) {
    const int b0 = (ch * 4 + wid) * 16;
#pragma unroll
    for (int r = 0; r < 4; ++r) {
      const int row = b0 + l4 * 4 + r;
      creg[ch][r] = c0[(size_t)row * HHD + u];
      kc[ch][r] = 1.f - done[row];
      kn[ch][r] = 1.f - done[BB + row];
    }
#pragma unroll
    for (int g = 0; g < 4; ++g)
#pragma unroll
      for (int r = 0; r < 4; ++r)
        xpf[ch][g * 4 + r] = xg[(size_t)(b0 + l4 * 4 + r) * GGD + g * HHD + u];
  }

  for (int t = 0; t < TT; ++t) {
    const u16* hsrc = hring + (size_t)(t & 1) * (BB * HHD);
    u16* hdst = hring + (size_t)((t + 1) & 1) * (BB * HHD);

#pragma unroll
    for (int ch = 0; ch < 4; ++ch) {
      const int rg = ch * 4 + wid;
      const int b0 = rg * 16;
      const int mrow = l4 * 4;

      if (t > 0) {  // wait until all 32 ug-producers published h(t) for this rg
        for (;;) {
          u32 v = 1;
          if (lane < 32)
            v = __hip_atomic_load(&slots[((size_t)rg * TT + (t - 1)) * 32 + lane],
                                  __ATOMIC_RELAXED, __HIP_MEMORY_SCOPE_AGENT);
          if (__all(v != 0)) break;
          __builtin_amdgcn_s_sleep(1);
        }
      }

      // A-frags from LLC (sc1, compiler-tracked vmcnt)
      u64 aflo[16], afhi[16];
      const u64* hb = (const u64*)(hsrc + (size_t)(b0 + l15) * HHD);
#pragma unroll
      for (int kk = 0; kk < 16; ++kk) {
        aflo[kk] = __hip_atomic_load(hb + kk * 8 + l4 * 2,
                                     __ATOMIC_RELAXED, __HIP_MEMORY_SCOPE_AGENT);
        afhi[kk] = __hip_atomic_load(hb + kk * 8 + l4 * 2 + 1,
                                     __ATOMIC_RELAXED, __HIP_MEMORY_SCOPE_AGENT);
      }

      // acc init from CURRENT xpf (VALU), then overwrite xpf with t+1 prefetch
      f32x4 acc[4];
#pragma unroll
      for (int g = 0; g < 4; ++g)
#pragma unroll
        for (int r = 0; r < 4; ++r)
          acc[g][r] = bf2f(xpf[ch][g * 4 + r]);
#pragma unroll
      for (int g = 0; g < 4; ++g) fence_mfma_srcc(acc[g]);  // VALU->MFMA SrcC hazard

      if (t < TT - 1) {  // issue early: retires under MFMA+gates
#pragma unroll
        for (int g = 0; g < 4; ++g)
#pragma unroll
          for (int r = 0; r < 4; ++r)
            xpf[ch][g * 4 + r] =
                xg[((size_t)(t + 1) * BB + b0 + mrow + r) * GGD + g * HHD + u];
      }

#pragma unroll
      for (int kk = 0; kk < 16; ++kk) {
        union { u64 q[2]; s16x8 v; } tmp;
        tmp.q[0] = aflo[kk]; tmp.q[1] = afhi[kk];
        s16x8 a = tmp.v;
#pragma unroll
        for (int g = 0; g < 4; ++g) {
          int br = g * 16 + l15;
          s16x8 b = *(const s16x8*)(wsm + ((br * 1024 + kk * 64 + l4 * 16) ^ ((br & 7) << 4)));
          acc[g] = mfma16x16x32(a, b, acc[g]);
        }
      }
#pragma unroll
      for (int g = 0; g < 4; ++g) fence_mfma_read(acc[g]);  // drain XDL before VALU

      float hv_[4], cv_[4];
#pragma unroll
      for (int r = 0; r < 4; ++r) {
        float iv = sigm(acc[0][r]);
        float fv = sigm(acc[1][r]);
        float gv = tanh_fast(acc[2][r]);
        float ov = sigm(acc[3][r]);
        float c = fv * (creg[ch][r] * kc[ch][r]) + iv * gv;
        float h = ov * tanh_fast(c);
        creg[ch][r] = c; cv_[r] = c; hv_[r] = h;
      }

      if (t < TT - 1) {
        // hs stores first (removed from next segment's vmcnt shadow)
#pragma unroll
        for (int r = 0; r < 4; ++r)
          hs[((size_t)t * BB + b0 + mrow + r) * HHD + u] = f2bf(hv_[r]);
        // publish h(t+1)*keep(t+1): paired-lane packed u32 sc1 stores
        u32 pw[4];
#pragma unroll
        for (int r = 0; r < 4; ++r) {
          u16 ob = f2bf(hv_[r] * kn[ch][r]);
          u16 pb = (u16)__shfl_xor((int)ob, 1, 64);
          pw[r] = ((l15 & 1) == 0) ? ((u32)ob | ((u32)pb << 16))
                                   : ((u32)pb | ((u32)ob << 16));
        }
        {
          const int rb = (l15 & 1) * 2;
          u32* hd32 = (u32*)hdst;
          const int col2 = (u0 + (l15 & ~1)) >> 1;
          __hip_atomic_store(&hd32[(size_t)(b0 + mrow + rb) * 256 + col2], pw[rb],
                             __ATOMIC_RELAXED, __HIP_MEMORY_SCOPE_AGENT);
          __hip_atomic_store(&hd32[(size_t)(b0 + mrow + rb + 1) * 256 + col2], pw[rb + 1],
                             __ATOMIC_RELAXED, __HIP_MEMORY_SCOPE_AGENT);
        }
        // drain publishes to LLC, then one-shot slot store (no RMW)
        asm volatile("s_waitcnt vmcnt(0)" ::: "memory");
        if (lane == 0)
          __hip_atomic_store(&slots[((size_t)rg * TT + t) * 32 + ug], 1u,
                             __ATOMIC_RELAXED, __HIP_MEMORY_SCOPE_AGENT);
        // keep rotate
#pragma unroll
        for (int r = 0; r < 4; ++r) {
          kc[ch][r] = kn[ch][r];
          kn[ch][r] = (t + 2 < TT) ? (1.f - done[(size_t)(t + 2) * BB + b0 + mrow + r]) : 1.f;
        }
      } else {
#pragma unroll
        for (int r = 0; r < 4; ++r) {
          hs[((size_t)t * BB + b0 + mrow + r) * HHD + u] = f2bf(hv_[r]);
          hT[(size_t)(b0 + mrow + r) * HHD + u] = hv_[r];
          cT[(size_t)(b0 + mrow + r) * HHD + u] = cv_[r];
        }
      }
    }
  }
}

// ---------------- final heads: adv(18) + val + dueling combine ----------------
__global__ __launch_bounds__(256) void head_final(
    const u16* __restrict__ hv, const u16* __restrict__ aW1T,
    const u16* __restrict__ vW1T, const float* __restrict__ ab1,
    const float* __restrict__ vb1, float* __restrict__ q)
{
  __shared__ __align__(16) u16 wa[AD * HHD];
  __shared__ __align__(16) u16 wv[HHD];
  const int tid = threadIdx.x;
  for (int i = tid; i < AD * HHD / 8; i += 256) ((uint4*)wa)[i] = ((const uint4*)aW1T)[i];
  for (int i = tid; i < HHD / 8; i += 256) ((uint4*)wv)[i] = ((const uint4*)vW1T)[i];
  __syncthreads();
  const int wid = tid >> 6, lane = tid & 63;
  for (int row = blockIdx.x * 4 + wid; row < MMD; row += gridDim.x * 4) {
    uint4 va = *(const uint4*)(hv + (size_t)row * 1024 + lane * 8);
    uint4 vv = *(const uint4*)(hv + (size_t)row * 1024 + 512 + lane * 8);
    const u16* pa = (const u16*)&va;
    const u16* pv = (const u16*)&vv;
    float af[8], vf[8];
#pragma unroll
    for (int j = 0; j < 8; ++j) { af[j] = bf2f(pa[j]); vf[j] = bf2f(pv[j]); }
    float accs[19];
#pragma unroll
    for (int n = 0; n < 19; ++n) accs[n] = 0.f;
#pragma unroll
    for (int n = 0; n < AD; ++n) {
      const u16* w = wa + n * HHD + lane * 8;
#pragma unroll
      for (int j = 0; j < 8; ++j) accs[n] += af[j] * bf2f(w[j]);
    }
    {
      const u16* w = wv + lane * 8;
#pragma unroll
      for (int j = 0; j < 8; ++j) accs[18] += vf[j] * bf2f(w[j]);
    }
#pragma unroll
    for (int n = 0; n < 19; ++n) {
#pragma unroll
      for (int off = 32; off > 0; off >>= 1)
        accs[n] += __shfl_xor(accs[n], off, 64);
    }
    if (lane == 0) {
      float s = 0.f;
      float advv[AD];
#pragma unroll
      for (int n = 0; n < AD; ++n) { advv[n] = accs[n] + ab1[n]; s += advv[n]; }
      float val = accs[18] + vb1[0];
      float mean = s * (1.f / 18.f);
#pragma unroll
      for (int n = 0; n < AD; ++n) q[(size_t)row * AD + n] = val + advv[n] - mean;
    }
  }
}

// ---------------- launch ----------------
extern "C" void kernel_launch(void* const* d_in, const int* in_sizes, int n_in,
                              void* d_out, int out_size, void* d_ws, size_t ws_size,
                              hipStream_t stream) {
  const float* o    = (const float*)d_in[0];
  const int*   a    = (const int*)d_in[1];
  const float* r    = (const float*)d_in[2];
  const float* done = (const float*)d_in[3];
  const float* h0   = (const float*)d_in[4];
  const float* c0   = (const float*)d_in[5];
  const float* tW0  = (const float*)d_in[6];
  const float* tb0  = (const float*)d_in[7];
  const float* tW1  = (const float*)d_in[8];
  const float* tb1  = (const float*)d_in[9];
  const float* Wih  = (const float*)d_in[10];
  const float* Whh  = (const float*)d_in[11];
  const float* bih  = (const float*)d_in[12];
  const float* bhh  = (const float*)d_in[13];
  const float* aW0  = (const float*)d_in[14];
  const float* ab0  = (const float*)d_in[15];
  const float* aW1  = (const float*)d_in[16];
  const float* ab1  = (const float*)d_in[17];
  const float* vW0  = (const float*)d_in[18];
  const float* vb0  = (const float*)d_in[19];
  const float* vW1  = (const float*)d_in[20];
  const float* vb1  = (const float*)d_in[21];
  (void)in_sizes; (void)n_in; (void)ws_size;

  char* ws = (char*)d_ws;
  u32* slots  = (u32*)(ws + OFF_FLAGS);
  u16* hring  = (u16*)(ws + OFF_HRING);
  u16* tW0T   = (u16*)(ws + OFF_TW0T);
  u16* tW1T   = (u16*)(ws + OFF_TW1T);
  u16* aW0T   = (u16*)(ws + OFF_AW0T);  // aW0T||vW0T contiguous => [1024][512]
  u16* vW0T   = (u16*)(ws + OFF_VW0T);
  u16* aW1T   = (u16*)(ws + OFF_AW1T);
  u16* vW1T   = (u16*)(ws + OFF_VW1T);
  u16* WihB   = (u16*)(ws + OFF_WIH);
  u16* WhhB   = (u16*)(ws + OFF_WHH);
  float* bsum = (float*)(ws + OFF_BSUM);
  float* wrc  = (float*)(ws + OFF_WRC);
  float* wemb = (float*)(ws + OFF_WEMB);
  float* bcat = (float*)(ws + OFF_BCAT);
  u16* o_bf   = (u16*)(ws + OFF_OBF);
  u16* buf1   = (u16*)(ws + OFF_BUF1);  // h1, later hs
  u16* buf2   = (u16*)(ws + OFF_BUF2);  // hid
  u16* buf3   = (u16*)(ws + OFF_BUF3);  // xg, later hv

  float* qout = (float*)d_out;
  float* hT   = qout + (size_t)TT * BB * AD;
  float* cT   = hT + (size_t)BB * HHD;

  hipMemsetAsync(slots, 0, 262144, stream);
  prep<<<2048, 256, 0, stream>>>(o, tW0, tW1, aW0, vW0, aW1, vW1, Wih, Whh,
                                 bih, bhh, h0, done, ab0, vb0,
                                 o_bf, tW0T, tW1T, aW0T, vW0T, aW1T, vW1T,
                                 WihB, WhhB, bsum, wrc, wemb, bcat, hring);
  gemm_bt<0><<<1024, 256, 0, stream>>>(o_bf, tW0T, buf1, MMD, 512, 128, tb0,
                                       nullptr, nullptr, nullptr, nullptr);
  gemm_bt<0><<<1024, 256, 0, stream>>>(buf1, tW1T, buf2, MMD, 512, 512, tb1,
                                       nullptr, nullptr, nullptr, nullptr);
  gemm_bt<1><<<4096, 256, 0, stream>>>(buf2, WihB, buf3, MMD, 2048, 512, bsum,
                                       wrc, wemb, r, a);
  lstm_seq<<<32, 256, 0, stream>>>(buf3, WhhB, done, c0, hring,
                                   buf1 /*hs*/, hT, cT, slots);
  gemm_bt<0><<<2048, 256, 0, stream>>>(buf1 /*hs*/, aW0T, buf3 /*hv*/, MMD, 1024, 512, bcat,
                                       nullptr, nullptr, nullptr, nullptr);
  head_final<<<2048, 256, 0, stream>>>(buf3, aW1T, vW1T, ab1, vb1, qout);
}

// Round 12
// 1007.051 us; speedup vs baseline: 3.9151x; 3.9151x over previous
//
#include <hip/hip_runtime.h>
#include <cstdint>

typedef unsigned short u16;
typedef unsigned int u32;
typedef unsigned long long u64;
typedef float f32x4 __attribute__((ext_vector_type(4)));
typedef short s16x8 __attribute__((ext_vector_type(8)));

#define DEV static __device__ __forceinline__

#define TT 128
#define BB 256
#define OBSD 128
#define HHD 512
#define AD 18
#define GGD 2048
#define MMD 32768

DEV u16 f2bf(float f) {
  u32 u = __builtin_bit_cast(u32, f);
  u += 0x7fffu + ((u >> 16) & 1u);
  return (u16)(u >> 16);
}
DEV float bf2f(u16 h) { return __builtin_bit_cast(float, ((u32)h) << 16); }

DEV f32x4 mfma16x16x32(s16x8 a, s16x8 b, f32x4 c) {
  // D = A*B + C, C/D layout: col=lane&15, row=(lane>>4)*4+reg  [m89/m91]
  asm("v_mfma_f32_16x16x32_bf16 %0, %1, %2, %0" : "+v"(c) : "v"(a), "v"(b));
  return c;
}
// Inline-asm MFMA: hazard recognizer can't see it -> manual wait states (proven R3).
DEV void fence_mfma_read(f32x4& x) { asm volatile("s_nop 7" : "+v"(x)); }
DEV void fence_mfma_srcc(f32x4& x) { asm volatile("s_nop 1" : "+v"(x)); }
DEV void fence_valu_srca(s16x8& x) { asm volatile("s_nop 1" : "+v"(x)); }

// async global->LDS, 16B/lane; LDS dest is wave-uniform base + lane*16 (m97/m104)
typedef __attribute__((address_space(3))) char lds_char;
typedef __attribute__((address_space(1))) const char gl_char;
DEV void gload16(const char* g, char* l) {
  __builtin_amdgcn_global_load_lds((const gl_char*)g, (lds_char*)l, 16, 0, 0);
}

DEV float sigm(float x) { return 1.f / (1.f + __expf(-x)); }
DEV float tanh_fast(float x) {
  float t = __expf(-2.f * fabsf(x));
  float r = (1.f - t) / (1.f + t);
  return copysignf(r, x);
}

// ---------------- workspace layout (bytes), total ~218MB ----------------
constexpr size_t OFF_FLAGS = 0;          // 8KB arrive counters: (4bg x 4wid) x 128t x 4B
constexpr size_t OFF_HRING = 524288;     // 524288  (2 x [256][512] bf16, UNSCALED h)
constexpr size_t OFF_TW0T  = 1048576;    // 131072
constexpr size_t OFF_TW1T  = 1179648;    // 524288
constexpr size_t OFF_AW0T  = 1703936;    // 524288
constexpr size_t OFF_VW0T  = 2228224;    // 524288 (contiguous with AW0T => [1024][512])
constexpr size_t OFF_AW1T  = 2752512;    // 18432
constexpr size_t OFF_VW1T  = 2770944;    // 1024
constexpr size_t OFF_WIH   = 2772992;    // 2097152
constexpr size_t OFF_WHH   = 4870144;    // 2097152
constexpr size_t OFF_BSUM  = 6967296;    // 8192
constexpr size_t OFF_WRC   = 6975488;    // 8192
constexpr size_t OFF_WEMB  = 6983680;    // 147456
constexpr size_t OFF_BCAT  = 7131136;    // 4096
constexpr size_t OFF_OBF   = 8388608;    // 8388608
constexpr size_t OFF_BUF1  = 16777216;   // 33554432  (h1, later ah [32768][512])
constexpr size_t OFF_BUF2  = 50331648;   // 33554432  (hid, later vh [32768][512])
constexpr size_t OFF_BUF3  = 83886080;   // 134217728 (xg)

// ---------------- prep: convert/transpose weights, convert o, init h-ring ----------------
__global__ __launch_bounds__(256) void prep(
    const float* __restrict__ o, const float* __restrict__ tW0,
    const float* __restrict__ tW1, const float* __restrict__ aW0,
    const float* __restrict__ vW0, const float* __restrict__ aW1,
    const float* __restrict__ vW1, const float* __restrict__ Wih,
    const float* __restrict__ WhhF, const float* __restrict__ bih,
    const float* __restrict__ bhh, const float* __restrict__ h0,
    const float* __restrict__ ab0, const float* __restrict__ vb0,
    u16* __restrict__ o_bf, u16* __restrict__ tW0T, u16* __restrict__ tW1T,
    u16* __restrict__ aW0T, u16* __restrict__ vW0T, u16* __restrict__ aW1T,
    u16* __restrict__ vW1T, u16* __restrict__ WihB, u16* __restrict__ WhhB,
    float* __restrict__ bsum, float* __restrict__ wrc, float* __restrict__ wemb,
    float* __restrict__ bcat, u16* __restrict__ hring)
{
  const int total = 4178432;
  for (int id = blockIdx.x * 256 + threadIdx.x; id < total; id += gridDim.x * 256) {
    int i = id;
    if (i < 1048576) {  // o -> bf16, x4
      float4 v = ((const float4*)o)[i];
      u16* dst = o_bf + (size_t)i * 4;
      dst[0] = f2bf(v.x); dst[1] = f2bf(v.y); dst[2] = f2bf(v.z); dst[3] = f2bf(v.w);
      continue;
    }
    i -= 1048576;
    if (i < 65536)  { int n = i >> 7, k = i & 127; tW0T[i] = f2bf(tW0[k * 512 + n]); continue; }
    i -= 65536;
    if (i < 262144) { int n = i >> 9, k = i & 511; tW1T[i] = f2bf(tW1[k * 512 + n]); continue; }
    i -= 262144;
    if (i < 262144) { int n = i >> 9, k = i & 511; aW0T[i] = f2bf(aW0[k * 512 + n]); continue; }
    i -= 262144;
    if (i < 262144) { int n = i >> 9, k = i & 511; vW0T[i] = f2bf(vW0[k * 512 + n]); continue; }
    i -= 262144;
    if (i < 9216)   { int n = i >> 9, k = i & 511; aW1T[i] = f2bf(aW1[k * 18 + n]); continue; }
    i -= 9216;
    if (i < 512)    { vW1T[i] = f2bf(vW1[i]); continue; }
    i -= 512;
    if (i < 1048576){ int g = i >> 9, k = i & 511; WihB[i] = f2bf(Wih[g * 531 + k]); continue; }
    i -= 1048576;
    if (i < 1048576){ WhhB[i] = f2bf(WhhF[i]); continue; }
    i -= 1048576;
    if (i < 2048)   { bsum[i] = bih[i] + bhh[i]; wrc[i] = Wih[i * 531 + 512]; continue; }
    i -= 2048;
    if (i < 36864)  { int j = i >> 11, g = i & 2047; wemb[i] = Wih[g * 531 + 513 + j]; continue; }
    i -= 36864;
    if (i < 1024)   { bcat[i] = (i < 512) ? ab0[i] : vb0[i - 512]; continue; }
    i -= 1024;
    { hring[i] = f2bf(h0[i]); }  // UNSCALED h0; consumer applies keep(0) mask
  }
}

// ---------------- bf16 MFMA GEMM: C[M][N] = A[M][K] * Bt[N][K]^T + epilogue ----------------
// MODE 0: relu(acc + bias[n]) -> bf16
// MODE 1: acc + bias[n] + r[m]*wrc[n] + wemb[a[m]][n] -> bf16 (xg epilogue)
template<int MODE>
__global__ __launch_bounds__(256) void gemm_bt(
    const u16* __restrict__ A, const u16* __restrict__ Bt, u16* __restrict__ C,
    int Mdim, int Ndim, int Kdim,
    const float* __restrict__ bias,
    const float* __restrict__ wrc, const float* __restrict__ wemb,
    const float* __restrict__ rin, const int* __restrict__ ain)
{
  __shared__ __align__(16) char smem[32768];  // A tile 16KB | B tile 16KB
  const int tid = threadIdx.x;
  const int nTn = Ndim >> 7;
  int wg = blockIdx.x;
  {  // XCD-aware swizzle (grid % 8 == 0 for all our launches)
    const int per = gridDim.x >> 3;
    wg = (wg & 7) * per + (wg >> 3);
  }
  const int tm = wg / nTn, tn = wg % nTn;
  const int wid = tid >> 6, lane = tid & 63;
  const int wr = wid >> 1, wc = wid & 1;
  const int l15 = lane & 15, l4 = lane >> 4;

  f32x4 acc[4][4];
#pragma unroll
  for (int i = 0; i < 4; ++i)
#pragma unroll
    for (int j = 0; j < 4; ++j) acc[i][j] = f32x4{0.f, 0.f, 0.f, 0.f};

  const int srow = lane >> 3;
  const int scolb = ((lane & 7) * 16) ^ (srow << 4);
  const size_t kd2 = (size_t)Kdim * 2;
  const char* Abase = (const char*)(A + (size_t)tm * 128 * Kdim);
  const char* Bbase = (const char*)(Bt + (size_t)tn * 128 * Kdim);
  const char* ga[4]; const char* gb[4]; char* la[4]; char* lb[4];
#pragma unroll
  for (int j = 0; j < 4; ++j) {
    const int row = wid * 32 + j * 8 + srow;
    ga[j] = Abase + (size_t)row * kd2 + scolb;
    gb[j] = Bbase + (size_t)row * kd2 + scolb;
    la[j] = smem + wid * 4096 + j * 1024;
    lb[j] = smem + 16384 + wid * 4096 + j * 1024;
  }

  for (int k0 = 0; k0 < Kdim; k0 += 64) {
    const size_t kb = (size_t)k0 * 2;
#pragma unroll
    for (int j = 0; j < 4; ++j) {
      gload16(ga[j] + kb, la[j]);
      gload16(gb[j] + kb, lb[j]);
    }
    __syncthreads();
#pragma unroll
    for (int kk = 0; kk < 2; ++kk) {
      s16x8 af[4], bfr[4];
#pragma unroll
      for (int i = 0; i < 4; ++i) {
        int ar = wr * 64 + i * 16 + l15;
        af[i] = *(const s16x8*)(smem + ((ar * 128 + kk * 64 + l4 * 16) ^ ((ar & 7) << 4)));
        int br = wc * 64 + i * 16 + l15;
        bfr[i] = *(const s16x8*)(smem + 16384 + ((br * 128 + kk * 64 + l4 * 16) ^ ((br & 7) << 4)));
      }
#pragma unroll
      for (int i = 0; i < 4; ++i)
#pragma unroll
        for (int j = 0; j < 4; ++j)
          acc[i][j] = mfma16x16x32(af[i], bfr[j], acc[i][j]);
    }
    __syncthreads();
  }

#pragma unroll
  for (int i = 0; i < 4; ++i)
#pragma unroll
    for (int j = 0; j < 4; ++j) fence_mfma_read(acc[i][j]);

#pragma unroll
  for (int i = 0; i < 4; ++i) {
    const int rowb = tm * 128 + wr * 64 + i * 16 + l4 * 4;
    float rv[4]; int av[4];
    if (MODE == 1) {
#pragma unroll
      for (int r = 0; r < 4; ++r) { rv[r] = rin[rowb + r]; av[r] = ain[rowb + r]; }
    }
#pragma unroll
    for (int j = 0; j < 4; ++j) {
      const int col = tn * 128 + wc * 64 + j * 16 + l15;
      const float bs = bias[col];
      if (MODE == 0) {
#pragma unroll
        for (int r = 0; r < 4; ++r) {
          float x = acc[i][j][r] + bs;
          x = fmaxf(x, 0.f);
          C[(size_t)(rowb + r) * Ndim + col] = f2bf(x);
        }
      } else {
        const float wcv = wrc[col];
#pragma unroll
        for (int r = 0; r < 4; ++r) {
          float x = acc[i][j][r] + bs + rv[r] * wcv + wemb[av[r] * GGD + col];
          C[(size_t)(rowb + r) * Ndim + col] = f2bf(x);
        }
      }
    }
  }
}

// ---------------- persistent LSTM scan (R10 base) + FUSED head GEMM ----------------
// 128 blocks = 4 bg x 32 ug; wave-decoupled per-(bg,wid) arrive counters (R10).
// hring holds UNSCALED h(t); consumer applies keep(t) as a per-lane u64 AND-mask
// (done is exactly 0/1) on A-frags for the recurrence; the UNMASKED A-frags
// (= hs[t-1] rows, fully held in regs) feed the fused head GEMM (32 MFMAs/wave,
// weights in 32KB LDS) inside the poll window -> downstream head GEMM eliminated.
__global__ __launch_bounds__(256, 1) void lstm_seq(
    const u16* __restrict__ xg, const u16* __restrict__ WhhB,
    const u16* __restrict__ WheadT, const float* __restrict__ done,
    const float* __restrict__ c0, const float* __restrict__ bcat,
    u16* __restrict__ hring, u16* __restrict__ ah, u16* __restrict__ vh,
    float* __restrict__ hT, float* __restrict__ cT, u32* __restrict__ cnt)
{
  __shared__ __align__(16) char wsm[65536];
  __shared__ __align__(16) char whd[32768];
  const int tid = threadIdx.x;
  const int bg = blockIdx.x & 3;
  const int ug = blockIdx.x >> 2;
  const int b0 = bg * 64;
  const int u0 = ug * 16;
  const int hc0 = ug * 32;   // head cols [hc0, hc0+32) of 1024

#pragma unroll
  for (int i = 0; i < 16; ++i) {  // W_hh slice: local row lr = gate*16+uu
    int idx = i * 256 + tid;
    int lr = idx >> 6, c8 = idx & 63;
    int g = lr >> 4, uu = lr & 15;
    uint4 v = *(const uint4*)(WhhB + (size_t)(g * 512 + u0 + uu) * 512 + c8 * 8);
    *(uint4*)(wsm + ((lr * 1024 + c8 * 16) ^ ((lr & 7) << 4))) = v;
  }
#pragma unroll
  for (int i = 0; i < 8; ++i) {   // head weight slice: rows hc0..hc0+32 of [1024][512]
    int idx = i * 256 + tid;
    int lr = idx >> 6, c8 = idx & 63;
    uint4 v = *(const uint4*)(WheadT + (size_t)(hc0 + lr) * 512 + c8 * 8);
    *(uint4*)(whd + ((lr * 1024 + c8 * 16) ^ ((lr & 7) << 4))) = v;
  }
  __syncthreads();  // once, before the loop

  const int wid = tid >> 6, lane = tid & 63;
  const int l15 = lane & 15, l4 = lane >> 4;
  const int mrow = wid * 16 + l4 * 4;
  const int afrow = b0 + wid * 16 + l15;
  const int u = u0 + l15;
  u32* const mycnt = cnt + ((bg << 2) | wid) * TT;

  u16* const hvout = (ug < 16) ? ah : vh;
  const int hcl = (ug < 16) ? hc0 : hc0 - 512;
  float bcv[2];
#pragma unroll
  for (int j = 0; j < 2; ++j) bcv[j] = bcat[hc0 + j * 16 + l15];

  float creg[4], kc[4];
#pragma unroll
  for (int r = 0; r < 4; ++r) {
    creg[r] = c0[(size_t)(b0 + mrow + r) * HHD + u];
    kc[r] = 1.f - done[b0 + mrow + r];
  }
  u64 am;
  { float dn = done[afrow]; am = (dn != 0.f) ? 0ull : ~0ull; }

  u16 xpf[16];
#pragma unroll
  for (int g = 0; g < 4; ++g)
#pragma unroll
    for (int r = 0; r < 4; ++r)
      xpf[g * 4 + r] = xg[(size_t)(b0 + mrow + r) * GGD + g * HHD + u];

  for (int t = 0; t < TT; ++t) {
    const u16* hsrc = hring + (size_t)(t & 1) * (BB * HHD);
    u16* hdst = hring + (size_t)((t + 1) & 1) * (BB * HHD);

    f32x4 acc[4];
#pragma unroll
    for (int g = 0; g < 4; ++g)
#pragma unroll
      for (int r = 0; r < 4; ++r)
        acc[g][r] = bf2f(xpf[g * 4 + r]);
#pragma unroll
    for (int g = 0; g < 4; ++g) fence_mfma_srcc(acc[g]);

    // A-frags: UNSCALED h(t-1), LLC-coherent u64 loads
    u64 aflo[16], afhi[16];
    const u64* hb = (const u64*)(hsrc + (size_t)afrow * HHD);
#pragma unroll
    for (int kk = 0; kk < 16; ++kk) {
      aflo[kk] = __hip_atomic_load(hb + kk * 8 + l4 * 2,
                                   __ATOMIC_RELAXED, __HIP_MEMORY_SCOPE_AGENT);
      afhi[kk] = __hip_atomic_load(hb + kk * 8 + l4 * 2 + 1,
                                   __ATOMIC_RELAXED, __HIP_MEMORY_SCOPE_AGENT);
    }
    // recurrent MFMAs, A masked on-the-fly by keep(t)[afrow] (done is 0/1)
#pragma unroll
    for (int kk = 0; kk < 16; ++kk) {
      union { u64 q[2]; s16x8 v; } tmp;
      tmp.q[0] = aflo[kk] & am; tmp.q[1] = afhi[kk] & am;
      s16x8 a = tmp.v;
      fence_valu_srca(a);  // v_and -> MFMA SrcA wait states
#pragma unroll
      for (int g = 0; g < 4; ++g) {
        int br = g * 16 + l15;
        s16x8 b = *(const s16x8*)(wsm + ((br * 1024 + kk * 64 + l4 * 16) ^ ((br & 7) << 4)));
        acc[g] = mfma16x16x32(a, b, acc[g]);
      }
    }
#pragma unroll
    for (int g = 0; g < 4; ++g) fence_mfma_read(acc[g]);

    float hv_[4], cv_[4];
#pragma unroll
    for (int r = 0; r < 4; ++r) {
      float iv = sigm(acc[0][r]);
      float fv = sigm(acc[1][r]);
      float gv = tanh_fast(acc[2][r]);
      float ov = sigm(acc[3][r]);
      float c = fv * (creg[r] * kc[r]) + iv * gv;
      float h = ov * tanh_fast(c);
      creg[r] = c; cv_[r] = c; hv_[r] = h;
    }

    // publish UNSCALED h(t): paired-lane packed u32 sc1 stores (always, incl. last)
    {
      u32 pw[4];
#pragma unroll
      for (int r = 0; r < 4; ++r) {
        u16 ob = f2bf(hv_[r]);
        u16 pb = (u16)__shfl_xor((int)ob, 1, 64);
        pw[r] = ((l15 & 1) == 0) ? ((u32)ob | ((u32)pb << 16))
                                 : ((u32)pb | ((u32)ob << 16));
      }
      const int rb = (l15 & 1) * 2;
      u32* hd32 = (u32*)hdst;
      const int col2 = (u0 + (l15 & ~1)) >> 1;
      __hip_atomic_store(&hd32[(size_t)(b0 + mrow + rb) * 256 + col2], pw[rb],
                         __ATOMIC_RELAXED, __HIP_MEMORY_SCOPE_AGENT);
      __hip_atomic_store(&hd32[(size_t)(b0 + mrow + rb + 1) * 256 + col2], pw[rb + 1],
                         __ATOMIC_RELAXED, __HIP_MEMORY_SCOPE_AGENT);
    }
    asm volatile("s_waitcnt vmcnt(0)" ::: "memory");
    if (lane == 0)
      __hip_atomic_fetch_add(&mycnt[t], 1u,
                             __ATOMIC_RELAXED, __HIP_MEMORY_SCOPE_AGENT);

    // ---- poll window: fused head GEMM for h(t-1) from UNMASKED A-frags ----
    if (t > 0) {
      f32x4 acch[2];
#pragma unroll
      for (int j = 0; j < 2; ++j)
#pragma unroll
        for (int r = 0; r < 4; ++r) acch[j][r] = bcv[j];
#pragma unroll
      for (int j = 0; j < 2; ++j) fence_mfma_srcc(acch[j]);
#pragma unroll
      for (int kk = 0; kk < 16; ++kk) {
        union { u64 q[2]; s16x8 v; } tmp;
        tmp.q[0] = aflo[kk]; tmp.q[1] = afhi[kk];
        s16x8 a = tmp.v;
#pragma unroll
        for (int j = 0; j < 2; ++j) {
          int br = j * 16 + l15;
          s16x8 b = *(const s16x8*)(whd + ((br * 1024 + kk * 64 + l4 * 16) ^ ((br & 7) << 4)));
          acch[j] = mfma16x16x32(a, b, acch[j]);
        }
      }
#pragma unroll
      for (int j = 0; j < 2; ++j) fence_mfma_read(acch[j]);
#pragma unroll
      for (int j = 0; j < 2; ++j)
#pragma unroll
        for (int r = 0; r < 4; ++r) {
          float x = fmaxf(acch[j][r], 0.f);
          hvout[((size_t)(t - 1) * BB + b0 + mrow + r) * 512 + hcl + j * 16 + l15] = f2bf(x);
        }
    }
    if (t == TT - 1) {
#pragma unroll
      for (int r = 0; r < 4; ++r) {
        hT[(size_t)(b0 + mrow + r) * HHD + u] = hv_[r];
        cT[(size_t)(b0 + mrow + r) * HHD + u] = cv_[r];
      }
    } else {
      // xg prefetch + keep/mask rotate (HBM latency retires under poll)
#pragma unroll
      for (int g = 0; g < 4; ++g)
#pragma unroll
        for (int r = 0; r < 4; ++r)
          xpf[g * 4 + r] = xg[((size_t)(t + 1) * BB + b0 + mrow + r) * GGD + g * HHD + u];
#pragma unroll
      for (int r = 0; r < 4; ++r)
        kc[r] = 1.f - done[(size_t)(t + 1) * BB + b0 + mrow + r];
      float dn = done[(size_t)(t + 1) * BB + afrow];
      am = (dn != 0.f) ? 0ull : ~0ull;
    }

    while (__hip_atomic_load(&mycnt[t],
                             __ATOMIC_RELAXED, __HIP_MEMORY_SCOPE_AGENT) < 32u)
      __builtin_amdgcn_s_sleep(1);
  }

  // ---- tail: head for h(TT-1) (published in iteration TT-1, poll done) ----
  {
    const u16* hfin = hring + (size_t)(TT & 1) * (BB * HHD);
    u64 aflo[16], afhi[16];
    const u64* hb = (const u64*)(hfin + (size_t)afrow * HHD);
#pragma unroll
    for (int kk = 0; kk < 16; ++kk) {
      aflo[kk] = __hip_atomic_load(hb + kk * 8 + l4 * 2,
                                   __ATOMIC_RELAXED, __HIP_MEMORY_SCOPE_AGENT);
      afhi[kk] = __hip_atomic_load(hb + kk * 8 + l4 * 2 + 1,
                                   __ATOMIC_RELAXED, __HIP_MEMORY_SCOPE_AGENT);
    }
    f32x4 acch[2];
#pragma unroll
    for (int j = 0; j < 2; ++j)
#pragma unroll
      for (int r = 0; r < 4; ++r) acch[j][r] = bcv[j];
#pragma unroll
    for (int j = 0; j < 2; ++j) fence_mfma_srcc(acch[j]);
#pragma unroll
    for (int kk = 0; kk < 16; ++kk) {
      union { u64 q[2]; s16x8 v; } tmp;
      tmp.q[0] = aflo[kk]; tmp.q[1] = afhi[kk];
      s16x8 a = tmp.v;
#pragma unroll
      for (int j = 0; j < 2; ++j) {
        int br = j * 16 + l15;
        s16x8 b = *(const s16x8*)(whd + ((br * 1024 + kk * 64 + l4 * 16) ^ ((br & 7) << 4)));
        acch[j] = mfma16x16x32(a, b, acch[j]);
      }
    }
#pragma unroll
    for (int j = 0; j < 2; ++j) fence_mfma_read(acch[j]);
#pragma unroll
    for (int j = 0; j < 2; ++j)
#pragma unroll
      for (int r = 0; r < 4; ++r) {
        float x = fmaxf(acch[j][r], 0.f);
        hvout[((size_t)(TT - 1) * BB + b0 + mrow + r) * 512 + hcl + j * 16 + l15] = f2bf(x);
      }
  }
}

// ---------------- final heads: adv(18) + val + dueling combine ----------------
__global__ __launch_bounds__(256) void head_final(
    const u16* __restrict__ ah, const u16* __restrict__ vh,
    const u16* __restrict__ aW1T, const u16* __restrict__ vW1T,
    const float* __restrict__ ab1, const float* __restrict__ vb1,
    float* __restrict__ q)
{
  __shared__ __align__(16) u16 wa[AD * HHD];
  __shared__ __align__(16) u16 wv[HHD];
  const int tid = threadIdx.x;
  for (int i = tid; i < AD * HHD / 8; i += 256) ((uint4*)wa)[i] = ((const uint4*)aW1T)[i];
  for (int i = tid; i < HHD / 8; i += 256) ((uint4*)wv)[i] = ((const uint4*)vW1T)[i];
  __syncthreads();
  const int wid = tid >> 6, lane = tid & 63;
  for (int row = blockIdx.x * 4 + wid; row < MMD; row += gridDim.x * 4) {
    uint4 va = *(const uint4*)(ah + (size_t)row * 512 + lane * 8);
    uint4 vv = *(const uint4*)(vh + (size_t)row * 512 + lane * 8);
    const u16* pa = (const u16*)&va;
    const u16* pv = (const u16*)&vv;
    float af[8], vf[8];
#pragma unroll
    for (int j = 0; j < 8; ++j) { af[j] = bf2f(pa[j]); vf[j] = bf2f(pv[j]); }
    float accs[19];
#pragma unroll
    for (int n = 0; n < 19; ++n) accs[n] = 0.f;
#pragma unroll
    for (int n = 0; n < AD; ++n) {
      const u16* w = wa + n * HHD + lane * 8;
#pragma unroll
      for (int j = 0; j < 8; ++j) accs[n] += af[j] * bf2f(w[j]);
    }
    {
      const u16* w = wv + lane * 8;
#pragma unroll
      for (int j = 0; j < 8; ++j) accs[18] += vf[j] * bf2f(w[j]);
    }
#pragma unroll
    for (int n = 0; n < 19; ++n) {
#pragma unroll
      for (int off = 32; off > 0; off >>= 1)
        accs[n] += __shfl_xor(accs[n], off, 64);
    }
    if (lane == 0) {
      float s = 0.f;
      float advv[AD];
#pragma unroll
      for (int n = 0; n < AD; ++n) { advv[n] = accs[n] + ab1[n]; s += advv[n]; }
      float val = accs[18] + vb1[0];
      float mean = s * (1.f / 18.f);
#pragma unroll
      for (int n = 0; n < AD; ++n) q[(size_t)row * AD + n] = val + advv[n] - mean;
    }
  }
}

// ---------------- launch ----------------
extern "C" void kernel_launch(void* const* d_in, const int* in_sizes, int n_in,
                              void* d_out, int out_size, void* d_ws, size_t ws_size,
                              hipStream_t stream) {
  const float* o    = (const float*)d_in[0];
  const int*   a    = (const int*)d_in[1];
  const float* r    = (const float*)d_in[2];
  const float* done = (const float*)d_in[3];
  const float* h0   = (const float*)d_in[4];
  const float* c0   = (const float*)d_in[5];
  const float* tW0  = (const float*)d_in[6];
  const float* tb0  = (const float*)d_in[7];
  const float* tW1  = (const float*)d_in[8];
  const float* tb1  = (const float*)d_in[9];
  const float* Wih  = (const float*)d_in[10];
  const float* Whh  = (const float*)d_in[11];
  const float* bih  = (const float*)d_in[12];
  const float* bhh  = (const float*)d_in[13];
  const float* aW0  = (const float*)d_in[14];
  const float* ab0  = (const float*)d_in[15];
  const float* aW1  = (const float*)d_in[16];
  const float* ab1  = (const float*)d_in[17];
  const float* vW0  = (const float*)d_in[18];
  const float* vb0  = (const float*)d_in[19];
  const float* vW1  = (const float*)d_in[20];
  const float* vb1  = (const float*)d_in[21];
  (void)in_sizes; (void)n_in; (void)ws_size;

  char* ws = (char*)d_ws;
  u32* cnt    = (u32*)(ws + OFF_FLAGS);
  u16* hring  = (u16*)(ws + OFF_HRING);
  u16* tW0T   = (u16*)(ws + OFF_TW0T);
  u16* tW1T   = (u16*)(ws + OFF_TW1T);
  u16* aW0T   = (u16*)(ws + OFF_AW0T);  // aW0T||vW0T contiguous => [1024][512]
  u16* vW0T   = (u16*)(ws + OFF_VW0T);
  u16* aW1T   = (u16*)(ws + OFF_AW1T);
  u16* vW1T   = (u16*)(ws + OFF_VW1T);
  u16* WihB   = (u16*)(ws + OFF_WIH);
  u16* WhhB   = (u16*)(ws + OFF_WHH);
  float* bsum = (float*)(ws + OFF_BSUM);
  float* wrc  = (float*)(ws + OFF_WRC);
  float* wemb = (float*)(ws + OFF_WEMB);
  float* bcat = (float*)(ws + OFF_BCAT);
  u16* o_bf   = (u16*)(ws + OFF_OBF);
  u16* buf1   = (u16*)(ws + OFF_BUF1);  // h1, later ah
  u16* buf2   = (u16*)(ws + OFF_BUF2);  // hid, later vh
  u16* buf3   = (u16*)(ws + OFF_BUF3);  // xg

  float* qout = (float*)d_out;
  float* hT   = qout + (size_t)TT * BB * AD;
  float* cT   = hT + (size_t)BB * HHD;

  hipMemsetAsync(cnt, 0, 65536, stream);
  prep<<<2048, 256, 0, stream>>>(o, tW0, tW1, aW0, vW0, aW1, vW1, Wih, Whh,
                                 bih, bhh, h0, ab0, vb0,
                                 o_bf, tW0T, tW1T, aW0T, vW0T, aW1T, vW1T,
                                 WihB, WhhB, bsum, wrc, wemb, bcat, hring);
  gemm_bt<0><<<1024, 256, 0, stream>>>(o_bf, tW0T, buf1, MMD, 512, 128, tb0,
                                       nullptr, nullptr, nullptr, nullptr);
  gemm_bt<0><<<1024, 256, 0, stream>>>(buf1, tW1T, buf2, MMD, 512, 512, tb1,
                                       nullptr, nullptr, nullptr, nullptr);
  gemm_bt<1><<<4096, 256, 0, stream>>>(buf2, WihB, buf3, MMD, 2048, 512, bsum,
                                       wrc, wemb, r, a);
  lstm_seq<<<128, 256, 0, stream>>>(buf3, WhhB, aW0T, done, c0, bcat, hring,
                                    buf1 /*ah*/, buf2 /*vh*/, hT, cT, cnt);
  head_final<<<2048, 256, 0, stream>>>(buf1, buf2, aW1T, vW1T, ab1, vb1, qout);
}